// Round 19
// baseline (86.711 us; speedup 1.0000x reference)
//
#include <hip/hip_runtime.h>

#define IMG 65536   // 256*256
#define W 256
#define H 256
#define RMAX 40     // truncated radius cap (t=19 tail at 40: ~2.6e-6 < 1e-5 budget)

// d_ws layout:
//   ktab: 20 x 256 floats (truncated, renormalized composed kernels; tap j at [8+j]), bytes [0, 20480)
//   ord : 192 ints at byte 20480 (images sorted by t desc)
//   rtab: 20 ints at byte 21248 (truncated radius per t, <= RMAX)
//   mid : 192*65536 floats at byte 32768 (intermediate H-pass output)

__global__ __launch_bounds__(256) void init_kernel(const int* __restrict__ t,
                                                   float* __restrict__ ktab,
                                                   int* __restrict__ ord,
                                                   int* __restrict__ rtab) {
  __shared__ double cur[256];
  __shared__ double sc[256];    // prefix-sum scratch
  __shared__ double base[11];
  __shared__ int keys[192];
  __shared__ int sRmax;
  int tid = threadIdx.x;
  int tt = blockIdx.x;          // 0..19
  if (tid == 0) {
    double p[11];
    double s = 0.0;
    for (int i = 0; i < 11; ++i) {
      double xx = (double)(i - 5) * 0.5;       // x / SIGMA, SIGMA=2
      p[i] = exp(-0.5 * xx * xx);
      s += p[i];
    }
    for (int i = 0; i < 11; ++i) base[i] = (double)(float)(p[i] / s);  // match np float32 taps
  }
  __syncthreads();

  if (tt == 0) {
    // identity kernel row (t=0 safety) + rank-sort images by t desc
    ktab[tid] = (tid == 8) ? 1.0f : 0.0f;
    if (tid == 0) rtab[0] = 0;
    if (tid < 192) keys[tid] = min(max(t[tid / 3], 0), 19);
    __syncthreads();
    if (tid < 192) {
      int k = keys[tid];
      int rank = 0;
      for (int j = 0; j < 192; ++j) {
        int kj = keys[j];
        if (kj > k || (kj == k && j < tid)) ++rank;
      }
      ord[rank] = tid;
    }
    return;
  }

  cur[tid] = (tid < 11) ? base[tid] : 0.0;
  __syncthreads();
  for (int step = 2; step <= tt; ++step) {
    int Lprev = 10 * (step - 1) + 1;
    double a = 0.0;
    for (int i = 0; i < 11; ++i) {
      int jj = tid - i;
      if (jj >= 0 && jj < Lprev) a += base[i] * cur[jj];
    }
    __syncthreads();
    cur[tid] = a;
    __syncthreads();
  }
  // parallel inclusive prefix sum of cur -> sc (Hillis-Steele, 8 steps)
  sc[tid] = cur[tid];
  __syncthreads();
#pragma unroll
  for (int off = 1; off < 256; off <<= 1) {
    double tmp = (tid >= off) ? sc[tid - off] : 0.0;
    __syncthreads();
    sc[tid] += tmp;
    __syncthreads();
  }
  if (tid == 0) sRmax = 1;
  __syncthreads();
  // truncation: R = max r in [1,5t] with tail-outside-(r-1) > 1e-5  (monotone)
  int c = 5 * tt;
  double total = sc[255];
  if (tid >= 1 && tid <= c) {
    double Srm1 = sc[c + tid - 1] - sc[c - tid];     // window sum, radius tid-1
    if (total - Srm1 > 1e-5) atomicMax(&sRmax, tid);
  }
  __syncthreads();
  int Rk = min(sRmax, RMAX);                         // cap for staged-halo kernels
  double ksum = sc[c + Rk] - ((c - Rk - 1 >= 0) ? sc[c - Rk - 1] : 0.0);
  double scale = 1.0 / ksum;                         // renormalize kept mass to 1
  if (tid == 0) rtab[tt] = Rk;
  int c0 = c - Rk;
  int Lk = 2 * Rk + 1;
  ktab[tt * 256 + tid] =
      (tid >= 8 && tid < 8 + Lk) ? (float)(cur[tid - 8 + c0] * scale) : 0.0f;
}

// H-pass: conv along h. Block = (16-wide w-tile) x (full 256 rows), grid (16,192).
// ROUND-18 POSTMORTEM: useful-FMA is 12.8us/pass but wall ~36-40us in EVERY
// variant since r13; VALUBusy tracks FMA/wall => pure latency exposure. The
// un-restored knob is OCCUPANCY: 45KB tiles -> 3 blocks/CU (23% occ) since r13;
// r12's 17KB hpass at 8/CU ran 53% occ. THIS ROUND: single-window transposed
// tile [16][352] = 22.5 KB -> 6-7 blocks/CU (launch_bounds(256,7)). Bonus: at
// 16 cols the (col&7)<<2 swizzle is 2-way on b128 (free) vs 4-way at 32 cols.
// Stores: lane-contiguous 64B per 16 lanes (r12-proven clean at 8/CU).
__global__ __launch_bounds__(256, 7) void hpass_kernel(const float* __restrict__ x,
                                                       const int* __restrict__ t,
                                                       const float* __restrict__ ktab,
                                                       const int* __restrict__ ord,
                                                       const int* __restrict__ rtab,
                                                       float* __restrict__ out) {
  __shared__ float tile[16 * 352];            // transposed: [col][r], 22.5 KB
  int tid = threadIdx.x;
  int img = __builtin_amdgcn_readfirstlane(ord[blockIdx.y]);
  int wt = blockIdx.x;                        // 0..15
  int b = img / 3;
  int tv = __builtin_amdgcn_readfirstlane(min(max(t[b], 0), 19));
  int R = __builtin_amdgcn_readfirstlane(rtab[tv]);
  int L = 2 * R + 1;
  int d = (RMAX - R) & 3;
  const float* __restrict__ kt = ktab + tv * 256 + (8 - d);  // d-shifted tap base
  const float* src = x + (size_t)img * IMG + (wt << 4);
  float* dst = out + (size_t)img * IMG + (wt << 4);
  {
    int c4 = (tid & 3) << 2;                  // 0,4,8,12
    int r0 = tid >> 2;                        // 0..63
#pragma unroll
    for (int i = 0; i < 6; ++i) {
      int rr = r0 + (i << 6);                 // 0..383
      if (rr < 352) {
        int p = rr - RMAX;                    // -40..311
        int srow = 255 - abs(255 - abs(p));   // reflect (valid for |p| <= 510)
        float4 v = *reinterpret_cast<const float4*>(src + srow * W + c4);
        int rc = rr & ~3, rl = rr & 3;
        tile[(c4 + 0) * 352 + (rc ^ (((c4 + 0) & 7) << 2)) + rl] = v.x;
        tile[(c4 + 1) * 352 + (rc ^ (((c4 + 1) & 7) << 2)) + rl] = v.y;
        tile[(c4 + 2) * 352 + (rc ^ (((c4 + 2) & 7) << 2)) + rl] = v.z;
        tile[(c4 + 3) * 352 + (rc ^ (((c4 + 3) & 7) << 2)) + rl] = v.w;
      }
    }
  }
  __syncthreads();
  int col = tid & 15;
  int rgrp = tid >> 4;                        // 0..15
  int h0 = rgrp << 4;                         // window rows h0..h0+15
  int nIter = (L + d + 30) & ~15;             // >= L+d+15: covers j=L-1 for o=15
  int A = h0 + ((RMAX - R) & ~3);             // aligned sweep start (tile coords)
  int cb = col * 352;
  int swz = (col & 7) << 2;
  float acc[16], kq[16];
#pragma unroll
  for (int o = 0; o < 16; ++o) { acc[o] = 0.f; kq[o] = 0.f; }
  for (int jb = 0; jb < nIter; jb += 16) {
    float kn[16];
#pragma unroll
    for (int u = 0; u < 16; ++u) kn[u] = kt[jb + u];   // uniform -> s_load
    float va[16];
#pragma unroll
    for (int m = 0; m < 4; ++m) {
      int qa = A + jb + (m << 2);             // mult of 4
      float4 ta = *reinterpret_cast<const float4*>(&tile[cb + (qa ^ swz)]);
      va[4 * m + 0] = ta.x; va[4 * m + 1] = ta.y; va[4 * m + 2] = ta.z; va[4 * m + 3] = ta.w;
    }
#pragma unroll
    for (int u = 0; u < 16; ++u) {
      kq[u] = kn[u];
#pragma unroll
      for (int o = 0; o < 16; ++o) acc[o] += kq[(u - o) & 15] * va[u];
    }
  }
#pragma unroll
  for (int o = 0; o < 16; ++o) dst[(h0 + o) * W + col] = acc[o];
}

// W-pass: conv along w, mid -> out. Block = (32-row band) x (256 cols), grid (8,192).
// b128 scheme: stride 360 (mult of 4), aligned sweep + d-shifted taps,
// 16B-chunk XOR swizzle on both stage (b128 writes) and read. (r18, unchanged)
__global__ __launch_bounds__(256, 3) void wpass_split(const float* __restrict__ srcbuf,
                                                      const int* __restrict__ t,
                                                      const float* __restrict__ ktab,
                                                      const int* __restrict__ ord,
                                                      const int* __restrict__ rtab,
                                                      float* __restrict__ dstbuf) {
  __shared__ float tile[32 * 360];
  int tid = threadIdx.x;
  int img = __builtin_amdgcn_readfirstlane(ord[blockIdx.y]);
  int ht = blockIdx.x;                        // 0..7
  int b = img / 3;
  int tv = __builtin_amdgcn_readfirstlane(min(max(t[b], 0), 19));
  int R = __builtin_amdgcn_readfirstlane(rtab[tv]);
  int L = 2 * R + 1;
  int d = (RMAX - R) & 3;
  const float* __restrict__ kt = ktab + tv * 256 + (8 - d);
  const float* src = srcbuf + (size_t)img * IMG + (ht << 5) * W;
  float* dst = dstbuf + (size_t)img * IMG + (ht << 5) * W;
  {
    int srow = tid >> 3;                      // 0..31
    int jbase = tid & 7;
    const float* sp = src + srow * W;
    int sb = srow * 360;
    int sswz = (srow & 7) << 2;
#pragma unroll
    for (int k = 0; k < 11; ++k) {
      int j = jbase + (k << 3);               // 0..87
      int c0 = -RMAX + (j << 2);              // -40..308
      int q = j << 2;                         // tile col of c0 (mult of 4)
      float4 v;
      if (c0 >= 0 && c0 <= 252) {
        v = *reinterpret_cast<const float4*>(sp + c0);
      } else {
        int r0c = 255 - abs(255 - abs(c0 + 0));
        int r1c = 255 - abs(255 - abs(c0 + 1));
        int r2c = 255 - abs(255 - abs(c0 + 2));
        int r3c = 255 - abs(255 - abs(c0 + 3));
        v = make_float4(sp[r0c], sp[r1c], sp[r2c], sp[r3c]);
      }
      *reinterpret_cast<float4*>(&tile[sb + (q ^ sswz)]) = v;   // b128 write
    }
  }
  __syncthreads();
  int row = tid & 31;
  int wgrp = tid >> 5;                        // 0..7
  int w0 = wgrp << 4;                         // window A cols w0..w0+15; B = +128
  int nIter = (L + d + 30) & ~15;             // >= L+d+15
  int A = w0 + ((RMAX - R) & ~3);
  int cb = row * 360;
  int swz = (row & 7) << 2;
  float accA[16], accB[16], kq[16];
#pragma unroll
  for (int o = 0; o < 16; ++o) { accA[o] = 0.f; accB[o] = 0.f; kq[o] = 0.f; }
  for (int jb = 0; jb < nIter; jb += 16) {
    float kn[16];
#pragma unroll
    for (int u = 0; u < 16; ++u) kn[u] = kt[jb + u];
    float va[16], vb[16];
#pragma unroll
    for (int m = 0; m < 4; ++m) {
      int qa = A + jb + (m << 2);
      float4 ta = *reinterpret_cast<const float4*>(&tile[cb + (qa ^ swz)]);
      float4 tb = *reinterpret_cast<const float4*>(&tile[cb + ((qa + 128) ^ swz)]);
      va[4 * m + 0] = ta.x; va[4 * m + 1] = ta.y; va[4 * m + 2] = ta.z; va[4 * m + 3] = ta.w;
      vb[4 * m + 0] = tb.x; vb[4 * m + 1] = tb.y; vb[4 * m + 2] = tb.z; vb[4 * m + 3] = tb.w;
    }
#pragma unroll
    for (int u = 0; u < 16; ++u) {
      kq[u] = kn[u];
#pragma unroll
      for (int o = 0; o < 16; ++o) {
        float k = kq[(u - o) & 15];
        accA[o] += k * va[u];
        accB[o] += k * vb[u];
      }
    }
  }
  {
    float4 a0 = make_float4(accA[0], accA[1], accA[2], accA[3]);
    float4 a1 = make_float4(accA[4], accA[5], accA[6], accA[7]);
    float4 a2 = make_float4(accA[8], accA[9], accA[10], accA[11]);
    float4 a3 = make_float4(accA[12], accA[13], accA[14], accA[15]);
    float* oA = dst + row * W + w0;
    *reinterpret_cast<float4*>(oA + 0) = a0;
    *reinterpret_cast<float4*>(oA + 4) = a1;
    *reinterpret_cast<float4*>(oA + 8) = a2;
    *reinterpret_cast<float4*>(oA + 12) = a3;
    float4 b0 = make_float4(accB[0], accB[1], accB[2], accB[3]);
    float4 b1 = make_float4(accB[4], accB[5], accB[6], accB[7]);
    float4 b2 = make_float4(accB[8], accB[9], accB[10], accB[11]);
    float4 b3 = make_float4(accB[12], accB[13], accB[14], accB[15]);
    float* oB = oA + 128;
    *reinterpret_cast<float4*>(oB + 0) = b0;
    *reinterpret_cast<float4*>(oB + 4) = b1;
    *reinterpret_cast<float4*>(oB + 8) = b2;
    *reinterpret_cast<float4*>(oB + 12) = b3;
  }
}

// Fallback in-place W-pass (only if ws too small; same structure, io buffer).
__global__ __launch_bounds__(256, 3) void wpass_inplace(const int* __restrict__ t,
                                                        const float* __restrict__ ktab,
                                                        const int* __restrict__ ord,
                                                        const int* __restrict__ rtab,
                                                        float* __restrict__ io) {
  __shared__ float tile[32 * 360];
  int tid = threadIdx.x;
  int img = __builtin_amdgcn_readfirstlane(ord[blockIdx.y]);
  int ht = blockIdx.x;
  int b = img / 3;
  int tv = __builtin_amdgcn_readfirstlane(min(max(t[b], 0), 19));
  int R = __builtin_amdgcn_readfirstlane(rtab[tv]);
  int L = 2 * R + 1;
  int d = (RMAX - R) & 3;
  const float* __restrict__ kt = ktab + tv * 256 + (8 - d);
  float* basep = io + (size_t)img * IMG + (ht << 5) * W;
  {
    int srow = tid >> 3;
    int jbase = tid & 7;
    const float* sp = basep + srow * W;
    int sb = srow * 360;
    int sswz = (srow & 7) << 2;
#pragma unroll
    for (int k = 0; k < 11; ++k) {
      int j = jbase + (k << 3);
      int c0 = -RMAX + (j << 2);
      int q = j << 2;
      float4 v;
      if (c0 >= 0 && c0 <= 252) {
        v = *reinterpret_cast<const float4*>(sp + c0);
      } else {
        int r0c = 255 - abs(255 - abs(c0 + 0));
        int r1c = 255 - abs(255 - abs(c0 + 1));
        int r2c = 255 - abs(255 - abs(c0 + 2));
        int r3c = 255 - abs(255 - abs(c0 + 3));
        v = make_float4(sp[r0c], sp[r1c], sp[r2c], sp[r3c]);
      }
      *reinterpret_cast<float4*>(&tile[sb + (q ^ sswz)]) = v;
    }
  }
  __syncthreads();
  int row = tid & 31;
  int wgrp = tid >> 5;
  int w0 = wgrp << 4;
  int nIter = (L + d + 30) & ~15;
  int A = w0 + ((RMAX - R) & ~3);
  int cb = row * 360;
  int swz = (row & 7) << 2;
  float accA[16], accB[16], kq[16];
#pragma unroll
  for (int o = 0; o < 16; ++o) { accA[o] = 0.f; accB[o] = 0.f; kq[o] = 0.f; }
  for (int jb = 0; jb < nIter; jb += 16) {
    float kn[16];
#pragma unroll
    for (int u = 0; u < 16; ++u) kn[u] = kt[jb + u];
    float va[16], vb[16];
#pragma unroll
    for (int m = 0; m < 4; ++m) {
      int qa = A + jb + (m << 2);
      float4 ta = *reinterpret_cast<const float4*>(&tile[cb + (qa ^ swz)]);
      float4 tb = *reinterpret_cast<const float4*>(&tile[cb + ((qa + 128) ^ swz)]);
      va[4 * m + 0] = ta.x; va[4 * m + 1] = ta.y; va[4 * m + 2] = ta.z; va[4 * m + 3] = ta.w;
      vb[4 * m + 0] = tb.x; vb[4 * m + 1] = tb.y; vb[4 * m + 2] = tb.z; vb[4 * m + 3] = tb.w;
    }
#pragma unroll
    for (int u = 0; u < 16; ++u) {
      kq[u] = kn[u];
#pragma unroll
      for (int o = 0; o < 16; ++o) {
        float k = kq[(u - o) & 15];
        accA[o] += k * va[u];
        accB[o] += k * vb[u];
      }
    }
  }
  {
    float4 a0 = make_float4(accA[0], accA[1], accA[2], accA[3]);
    float4 a1 = make_float4(accA[4], accA[5], accA[6], accA[7]);
    float4 a2 = make_float4(accA[8], accA[9], accA[10], accA[11]);
    float4 a3 = make_float4(accA[12], accA[13], accA[14], accA[15]);
    float* oA = basep + row * W + w0;
    *reinterpret_cast<float4*>(oA + 0) = a0;
    *reinterpret_cast<float4*>(oA + 4) = a1;
    *reinterpret_cast<float4*>(oA + 8) = a2;
    *reinterpret_cast<float4*>(oA + 12) = a3;
    float4 b0 = make_float4(accB[0], accB[1], accB[2], accB[3]);
    float4 b1 = make_float4(accB[4], accB[5], accB[6], accB[7]);
    float4 b2 = make_float4(accB[8], accB[9], accB[10], accB[11]);
    float4 b3 = make_float4(accB[12], accB[13], accB[14], accB[15]);
    float* oB = oA + 128;
    *reinterpret_cast<float4*>(oB + 0) = b0;
    *reinterpret_cast<float4*>(oB + 4) = b1;
    *reinterpret_cast<float4*>(oB + 8) = b2;
    *reinterpret_cast<float4*>(oB + 12) = b3;
  }
}

extern "C" void kernel_launch(void* const* d_in, const int* in_sizes, int n_in,
                              void* d_out, int out_size, void* d_ws, size_t ws_size,
                              hipStream_t stream) {
  const float* x = (const float*)d_in[0];
  const int* t = (const int*)d_in[1];
  float* out = (float*)d_out;
  float* ktab = (float*)d_ws;
  int* ord = (int*)((char*)d_ws + 20480);
  int* rtab = (int*)((char*)d_ws + 21248);
  const size_t mid_off = 32768;
  const size_t mid_bytes = (size_t)192 * IMG * 4;

  hipLaunchKernelGGL(init_kernel, dim3(20), dim3(256), 0, stream, t, ktab, ord, rtab);
  if (ws_size >= mid_off + mid_bytes) {
    float* mid = (float*)((char*)d_ws + mid_off);
    hipLaunchKernelGGL(hpass_kernel, dim3(16, 192), dim3(256), 0, stream, x, t, ktab, ord, rtab, mid);
    hipLaunchKernelGGL(wpass_split, dim3(8, 192), dim3(256), 0, stream, mid, t, ktab, ord, rtab, out);
  } else {
    hipLaunchKernelGGL(hpass_kernel, dim3(16, 192), dim3(256), 0, stream, x, t, ktab, ord, rtab, out);
    hipLaunchKernelGGL(wpass_inplace, dim3(8, 192), dim3(256), 0, stream, t, ktab, ord, rtab, out);
  }
}

// Round 20
// 80.610 us; speedup vs baseline: 1.0757x; 1.0757x over previous
//
#include <hip/hip_runtime.h>

#define IMG 65536   // 256*256
#define W 256
#define H 256
#define RMAX 40     // truncated radius cap (t=19 tail at 40: ~2.6e-6 < 1e-5 budget)

// d_ws layout:
//   ktab: 20 x 256 floats (truncated, renormalized composed kernels; tap j at [8+j]), bytes [0, 20480)
//   ord : 192 ints at byte 20480 (images sorted by t desc)
//   rtab: 20 ints at byte 21248 (truncated radius per t, <= RMAX)
//   mid : 192*65536 floats at byte 32768 (intermediate H-pass output)

__global__ __launch_bounds__(256) void init_kernel(const int* __restrict__ t,
                                                   float* __restrict__ ktab,
                                                   int* __restrict__ ord,
                                                   int* __restrict__ rtab) {
  __shared__ double cur[256];
  __shared__ double sc[256];    // prefix-sum scratch
  __shared__ double base[11];
  __shared__ int keys[192];
  __shared__ int sRmax;
  int tid = threadIdx.x;
  int tt = blockIdx.x;          // 0..19
  if (tid == 0) {
    double p[11];
    double s = 0.0;
    for (int i = 0; i < 11; ++i) {
      double xx = (double)(i - 5) * 0.5;       // x / SIGMA, SIGMA=2
      p[i] = exp(-0.5 * xx * xx);
      s += p[i];
    }
    for (int i = 0; i < 11; ++i) base[i] = (double)(float)(p[i] / s);  // match np float32 taps
  }
  __syncthreads();

  if (tt == 0) {
    // identity kernel row (t=0 safety) + rank-sort images by t desc
    ktab[tid] = (tid == 8) ? 1.0f : 0.0f;
    if (tid == 0) rtab[0] = 0;
    if (tid < 192) keys[tid] = min(max(t[tid / 3], 0), 19);
    __syncthreads();
    if (tid < 192) {
      int k = keys[tid];
      int rank = 0;
      for (int j = 0; j < 192; ++j) {
        int kj = keys[j];
        if (kj > k || (kj == k && j < tid)) ++rank;
      }
      ord[rank] = tid;
    }
    return;
  }

  cur[tid] = (tid < 11) ? base[tid] : 0.0;
  __syncthreads();
  for (int step = 2; step <= tt; ++step) {
    int Lprev = 10 * (step - 1) + 1;
    double a = 0.0;
    for (int i = 0; i < 11; ++i) {
      int jj = tid - i;
      if (jj >= 0 && jj < Lprev) a += base[i] * cur[jj];
    }
    __syncthreads();
    cur[tid] = a;
    __syncthreads();
  }
  // parallel inclusive prefix sum of cur -> sc (Hillis-Steele, 8 steps)
  sc[tid] = cur[tid];
  __syncthreads();
#pragma unroll
  for (int off = 1; off < 256; off <<= 1) {
    double tmp = (tid >= off) ? sc[tid - off] : 0.0;
    __syncthreads();
    sc[tid] += tmp;
    __syncthreads();
  }
  if (tid == 0) sRmax = 1;
  __syncthreads();
  // truncation: R = max r in [1,5t] with tail-outside-(r-1) > 1e-5  (monotone)
  int c = 5 * tt;
  double total = sc[255];
  if (tid >= 1 && tid <= c) {
    double Srm1 = sc[c + tid - 1] - sc[c - tid];     // window sum, radius tid-1
    if (total - Srm1 > 1e-5) atomicMax(&sRmax, tid);
  }
  __syncthreads();
  int Rk = min(sRmax, RMAX);                         // cap for staged-halo kernels
  double ksum = sc[c + Rk] - ((c - Rk - 1 >= 0) ? sc[c - Rk - 1] : 0.0);
  double scale = 1.0 / ksum;                         // renormalize kept mass to 1
  if (tid == 0) rtab[tt] = Rk;
  int c0 = c - Rk;
  int Lk = 2 * Rk + 1;
  ktab[tt * 256 + tid] =
      (tid >= 8 && tid < 8 + Lk) ? (float)(cur[tid - 8 + c0] * scale) : 0.0f;
}

// H-pass (r18 BEST-MEASURED, verbatim: ~36us in the 81.4us run): 32-col
// transposed tile [32][352] b128 reads, dual-window (+128), d-shifted taps,
// 16B-chunk XOR swizzle on both stage and read, (256,3), grid (8,192).
__global__ __launch_bounds__(256, 3) void hpass_kernel(const float* __restrict__ x,
                                                       const int* __restrict__ t,
                                                       const float* __restrict__ ktab,
                                                       const int* __restrict__ ord,
                                                       const int* __restrict__ rtab,
                                                       float* __restrict__ out) {
  __shared__ float tile[32 * 352];            // transposed: [col][r], 45 KB -> 3/CU
  int tid = threadIdx.x;
  int img = __builtin_amdgcn_readfirstlane(ord[blockIdx.y]);
  int wt = blockIdx.x;                        // 0..7
  int b = img / 3;
  int tv = __builtin_amdgcn_readfirstlane(min(max(t[b], 0), 19));
  int R = __builtin_amdgcn_readfirstlane(rtab[tv]);
  int L = 2 * R + 1;
  int d = (RMAX - R) & 3;
  const float* __restrict__ kt = ktab + tv * 256 + (8 - d);  // d-shifted tap base
  const float* src = x + (size_t)img * IMG + (wt << 5);
  float* dst = out + (size_t)img * IMG + (wt << 5);
  {
    int c4 = (tid & 7) << 2;                  // 0..28
    int r0 = tid >> 3;                        // 0..31
#pragma unroll
    for (int i = 0; i < 11; ++i) {
      int rr = r0 + (i << 5);                 // 0..351
      int p = rr - RMAX;                      // -40..311
      int srow = 255 - abs(255 - abs(p));     // reflect (valid for |p| <= 510)
      float4 v = *reinterpret_cast<const float4*>(src + srow * W + c4);
      int rc = rr & ~3, rl = rr & 3;
      tile[(c4 + 0) * 352 + (rc ^ (((c4 + 0) & 7) << 2)) + rl] = v.x;
      tile[(c4 + 1) * 352 + (rc ^ (((c4 + 1) & 7) << 2)) + rl] = v.y;
      tile[(c4 + 2) * 352 + (rc ^ (((c4 + 2) & 7) << 2)) + rl] = v.z;
      tile[(c4 + 3) * 352 + (rc ^ (((c4 + 3) & 7) << 2)) + rl] = v.w;
    }
  }
  __syncthreads();
  int col = tid & 31;
  int rgrp = tid >> 5;                        // 0..7
  int h0 = rgrp << 4;                         // window A rows h0..h0+15; B = +128
  int nIter = (L + d + 30) & ~15;             // >= L+d+15: covers j=L-1 for o=15
  int A = h0 + ((RMAX - R) & ~3);             // aligned sweep start (tile coords)
  int cb = col * 352;
  int swz = (col & 7) << 2;
  float accA[16], accB[16], kq[16];
#pragma unroll
  for (int o = 0; o < 16; ++o) { accA[o] = 0.f; accB[o] = 0.f; kq[o] = 0.f; }
  for (int jb = 0; jb < nIter; jb += 16) {
    float kn[16];
#pragma unroll
    for (int u = 0; u < 16; ++u) kn[u] = kt[jb + u];   // uniform -> s_load
    float va[16], vb[16];
#pragma unroll
    for (int m = 0; m < 4; ++m) {
      int qa = A + jb + (m << 2);             // mult of 4
      float4 ta = *reinterpret_cast<const float4*>(&tile[cb + (qa ^ swz)]);
      float4 tb = *reinterpret_cast<const float4*>(&tile[cb + ((qa + 128) ^ swz)]);
      va[4 * m + 0] = ta.x; va[4 * m + 1] = ta.y; va[4 * m + 2] = ta.z; va[4 * m + 3] = ta.w;
      vb[4 * m + 0] = tb.x; vb[4 * m + 1] = tb.y; vb[4 * m + 2] = tb.z; vb[4 * m + 3] = tb.w;
    }
#pragma unroll
    for (int u = 0; u < 16; ++u) {
      kq[u] = kn[u];
#pragma unroll
      for (int o = 0; o < 16; ++o) {
        float k = kq[(u - o) & 15];
        accA[o] += k * va[u];
        accB[o] += k * vb[u];
      }
    }
  }
#pragma unroll
  for (int o = 0; o < 16; ++o) {
    dst[(h0 + o) * W + col] = accA[o];
    dst[(h0 + 128 + o) * W + col] = accB[o];
  }
}

// W-pass (r14 BEST-MEASURED, verbatim: ~26us inferred from the r14 run):
// tile[32][361] (stride coprime to 32 -> conflict-free same-col reads),
// taps broadcast from ktile LDS, dual g-loop, float4 stores, (256,3), grid (8,192).
__global__ __launch_bounds__(256, 3) void wpass_split(const float* __restrict__ srcbuf,
                                                      const int* __restrict__ t,
                                                      const float* __restrict__ ktab,
                                                      const int* __restrict__ ord,
                                                      const int* __restrict__ rtab,
                                                      float* __restrict__ dstbuf) {
  __shared__ float tile[32 * 361];
  __shared__ float ktile[256];
  int tid = threadIdx.x;
  int img = __builtin_amdgcn_readfirstlane(ord[blockIdx.y]);
  int ht = blockIdx.x;                        // 0..7
  int b = img / 3;
  int tv = __builtin_amdgcn_readfirstlane(min(max(t[b], 0), 19));
  int R = __builtin_amdgcn_readfirstlane(rtab[tv]);
  int L = 2 * R + 1;
  const float* __restrict__ kt = ktab + tv * 256;
  const float* src = srcbuf + (size_t)img * IMG + (ht << 5) * W;
  float* dst = dstbuf + (size_t)img * IMG + (ht << 5) * W;
  ktile[tid] = kt[tid];                       // tap row -> LDS (1 KB)
  {
    int srow = tid >> 3;                      // 0..31
    int jbase = tid & 7;
    const float* sp = src + srow * W;
    float* tp0 = &tile[srow * 361];
#pragma unroll
    for (int k = 0; k < 11; ++k) {
      int j = jbase + (k << 3);               // 0..87
      int c0 = -RMAX + (j << 2);              // -40..308
      float* tp = tp0 + c0 + RMAX;
      if (c0 >= 0 && c0 <= 252) {
        float4 v = *reinterpret_cast<const float4*>(sp + c0);
        tp[0] = v.x; tp[1] = v.y; tp[2] = v.z; tp[3] = v.w;
      } else {
#pragma unroll
        for (int d = 0; d < 4; ++d) {
          int cc = c0 + d;
          int rc = 255 - abs(255 - abs(cc));  // reflect
          tp[d] = sp[rc];
        }
      }
    }
  }
  __syncthreads();
  int row = tid & 31;
  int wgrp = tid >> 5;                        // 0..7
  int rowbase = row * 361;
  int nIter = (L + 30) & ~15;
  for (int g = 0; g < 2; ++g) {
    int w0 = (wgrp << 5) + (g << 4);
    float acc[16];
    float kq[16];
#pragma unroll
    for (int o = 0; o < 16; ++o) { acc[o] = 0.f; kq[o] = 0.f; }
    int pb = w0 - R + RMAX;                   // tile-col base (>= 0; reads <= 350 < 361)
    for (int jb = 0; jb < nIter; jb += 16) {
#pragma unroll
      for (int u = 0; u < 16; ++u) {
        kq[u] = ktile[jb + u + 8];            // uniform addr -> LDS broadcast
        float v = tile[rowbase + pb + jb + u];
#pragma unroll
        for (int o = 0; o < 16; ++o) acc[o] += kq[(u - o) & 15] * v;
      }
    }
    float4 v0 = make_float4(acc[0], acc[1], acc[2], acc[3]);
    float4 v1 = make_float4(acc[4], acc[5], acc[6], acc[7]);
    float4 v2 = make_float4(acc[8], acc[9], acc[10], acc[11]);
    float4 v3 = make_float4(acc[12], acc[13], acc[14], acc[15]);
    float* o0 = dst + row * W + w0;
    *reinterpret_cast<float4*>(o0 + 0) = v0;
    *reinterpret_cast<float4*>(o0 + 4) = v1;
    *reinterpret_cast<float4*>(o0 + 8) = v2;
    *reinterpret_cast<float4*>(o0 + 12) = v3;
  }
}

// Fallback in-place W-pass (only if ws too small; same structure, io buffer).
__global__ __launch_bounds__(256, 3) void wpass_inplace(const int* __restrict__ t,
                                                        const float* __restrict__ ktab,
                                                        const int* __restrict__ ord,
                                                        const int* __restrict__ rtab,
                                                        float* __restrict__ io) {
  __shared__ float tile[32 * 361];
  __shared__ float ktile[256];
  int tid = threadIdx.x;
  int img = __builtin_amdgcn_readfirstlane(ord[blockIdx.y]);
  int ht = blockIdx.x;                        // 0..7
  int b = img / 3;
  int tv = __builtin_amdgcn_readfirstlane(min(max(t[b], 0), 19));
  int R = __builtin_amdgcn_readfirstlane(rtab[tv]);
  int L = 2 * R + 1;
  const float* __restrict__ kt = ktab + tv * 256;
  float* basep = io + (size_t)img * IMG + (ht << 5) * W;
  ktile[tid] = kt[tid];
  {
    int srow = tid >> 3;
    int jbase = tid & 7;
    const float* sp = basep + srow * W;
    float* tp0 = &tile[srow * 361];
#pragma unroll
    for (int k = 0; k < 11; ++k) {
      int j = jbase + (k << 3);
      int c0 = -RMAX + (j << 2);
      float* tp = tp0 + c0 + RMAX;
      if (c0 >= 0 && c0 <= 252) {
        float4 v = *reinterpret_cast<const float4*>(sp + c0);
        tp[0] = v.x; tp[1] = v.y; tp[2] = v.z; tp[3] = v.w;
      } else {
#pragma unroll
        for (int d = 0; d < 4; ++d) {
          int cc = c0 + d;
          int rc = 255 - abs(255 - abs(cc));
          tp[d] = sp[rc];
        }
      }
    }
  }
  __syncthreads();
  int row = tid & 31;
  int wgrp = tid >> 5;
  int rowbase = row * 361;
  int nIter = (L + 30) & ~15;
  for (int g = 0; g < 2; ++g) {
    int w0 = (wgrp << 5) + (g << 4);
    float acc[16];
    float kq[16];
#pragma unroll
    for (int o = 0; o < 16; ++o) { acc[o] = 0.f; kq[o] = 0.f; }
    int pb = w0 - R + RMAX;
    for (int jb = 0; jb < nIter; jb += 16) {
#pragma unroll
      for (int u = 0; u < 16; ++u) {
        kq[u] = ktile[jb + u + 8];
        float v = tile[rowbase + pb + jb + u];
#pragma unroll
        for (int o = 0; o < 16; ++o) acc[o] += kq[(u - o) & 15] * v;
      }
    }
    float4 v0 = make_float4(acc[0], acc[1], acc[2], acc[3]);
    float4 v1 = make_float4(acc[4], acc[5], acc[6], acc[7]);
    float4 v2 = make_float4(acc[8], acc[9], acc[10], acc[11]);
    float4 v3 = make_float4(acc[12], acc[13], acc[14], acc[15]);
    float* o0 = basep + row * W + w0;
    *reinterpret_cast<float4*>(o0 + 0) = v0;
    *reinterpret_cast<float4*>(o0 + 4) = v1;
    *reinterpret_cast<float4*>(o0 + 8) = v2;
    *reinterpret_cast<float4*>(o0 + 12) = v3;
  }
}

extern "C" void kernel_launch(void* const* d_in, const int* in_sizes, int n_in,
                              void* d_out, int out_size, void* d_ws, size_t ws_size,
                              hipStream_t stream) {
  const float* x = (const float*)d_in[0];
  const int* t = (const int*)d_in[1];
  float* out = (float*)d_out;
  float* ktab = (float*)d_ws;
  int* ord = (int*)((char*)d_ws + 20480);
  int* rtab = (int*)((char*)d_ws + 21248);
  const size_t mid_off = 32768;
  const size_t mid_bytes = (size_t)192 * IMG * 4;

  hipLaunchKernelGGL(init_kernel, dim3(20), dim3(256), 0, stream, t, ktab, ord, rtab);
  if (ws_size >= mid_off + mid_bytes) {
    float* mid = (float*)((char*)d_ws + mid_off);
    hipLaunchKernelGGL(hpass_kernel, dim3(8, 192), dim3(256), 0, stream, x, t, ktab, ord, rtab, mid);
    hipLaunchKernelGGL(wpass_split, dim3(8, 192), dim3(256), 0, stream, mid, t, ktab, ord, rtab, out);
  } else {
    hipLaunchKernelGGL(hpass_kernel, dim3(8, 192), dim3(256), 0, stream, x, t, ktab, ord, rtab, out);
    hipLaunchKernelGGL(wpass_inplace, dim3(8, 192), dim3(256), 0, stream, t, ktab, ord, rtab, out);
  }
}